// Round 4
// baseline (206.208 us; speedup 1.0000x reference)
//
#include <hip/hip_runtime.h>
#include <hip/hip_bf16.h>

typedef _Float16 f16x8 __attribute__((ext_vector_type(8)));
typedef _Float16 f16x4 __attribute__((ext_vector_type(4)));
typedef float f32x4 __attribute__((ext_vector_type(4)));
typedef unsigned int u32;

#define MFMA16(a, b, c) __builtin_amdgcn_mfma_f32_16x16x32_f16(a, b, c, 0, 0, 0)

// q pre-scale: sqrt(64) * log2(e)  (exp2-domain softmax)
#define QSCALE 11.54156032f

__device__ __forceinline__ void gld16(const void* g, void* l) {
  using gp_t = const __attribute__((address_space(1))) u32*;
  using lp_t = __attribute__((address_space(3))) u32*;
  __builtin_amdgcn_global_load_lds((gp_t)g, (lp_t)l, 16, 0, 0);
}

// ---------------- fp32 -> fp16 elementwise convert (x) ----------------
__global__ void conv_f32_f16(const float* __restrict__ in, _Float16* __restrict__ out) {
  int i = (blockIdx.x * 256 + threadIdx.x) * 4;
  float4 v = *(const float4*)(in + i);
  f16x4 h = {(_Float16)v.x, (_Float16)v.y, (_Float16)v.z, (_Float16)v.w};
  *(f16x4*)(out + i) = h;
}

// ---------------- fp32 [R][C] -> fp16 [C][R] transpose ----------------
__global__ void transpose_f32_f16(const float* __restrict__ in, _Float16* __restrict__ out,
                                  int R, int C) {
  __shared__ float t[32][33];
  const int tx = threadIdx.x, ty = threadIdx.y;
  const int bx = blockIdx.x * 32, by = blockIdx.y * 32;
  for (int i = 0; i < 32; i += 8)
    t[ty + i][tx] = in[(size_t)(by + ty + i) * C + bx + tx];
  __syncthreads();
  for (int i = 0; i < 32; i += 8)
    out[(size_t)(bx + ty + i) * R + by + tx] = (_Float16)t[tx][ty + i];
}

// ---------------- 128x128 tile GEMM, BK=64: C = A[M][K] * Bt[N][K]^T -------
// T2 swizzle: linear gld_lds dest + pre-swizzled global source col-block
// ((l&7)^(l>>3)), frag reads XOR by (row&7). T1 XCD swizzle on 1-D grid
// (gridM fixed = 32 m-tiles). MODE 0: QKV scatter epilogue. MODE 1: fp32 out.
template <int MODE>
__global__ __launch_bounds__(256) void gemm128(
    const _Float16* __restrict__ A, const _Float16* __restrict__ Bt, int Kd,
    _Float16* __restrict__ qo, _Float16* __restrict__ ko, _Float16* __restrict__ vt,
    float* __restrict__ fo, int Nd) {
  __shared__ __align__(16) _Float16 As[128 * 64];
  __shared__ __align__(16) _Float16 Bs[128 * 64];
  const int tid = threadIdx.x;
  const int w = tid >> 6, l = tid & 63;
  const int wm = w >> 1, wn = w & 1;
  const int lr = l & 15, lg = l >> 4;
  // XCD-aware swizzle (nwg % 8 == 0 for both launches)
  const int nwg = gridDim.x;
  int lin = blockIdx.x;
  lin = (lin & 7) * (nwg >> 3) + (lin >> 3);
  const int m0 = (lin & 31) * 128, n0 = (lin >> 5) * 128;

  // staging geometry: per call c, wave w covers rows c*32+w*8 .. +7 (128B each)
  const int srow = tid >> 3;                       // 0..31 (row within 32-row group)
  const int scol = ((tid & 7) ^ (srow & 7)) * 8;   // pre-swizzled source col (halves)
  const int swzr = (lr & 7) << 3;                  // read-side XOR (halves)

  f32x4 acc[4][4];
  for (int i = 0; i < 4; ++i)
    for (int j = 0; j < 4; ++j) acc[i][j] = (f32x4){0.f, 0.f, 0.f, 0.f};

  const int NT = Kd >> 6;
  for (int kt = 0; kt < NT; ++kt) {
    const int k0 = kt * 64;
    for (int c = 0; c < 4; ++c) {
      const int row = c * 32 + srow;
      const int lbase = (c * 32 + w * 8) * 64;  // wave-uniform dest (halves)
      gld16(A + (size_t)(m0 + row) * Kd + k0 + scol, &As[lbase]);
      gld16(Bt + (size_t)(n0 + row) * Kd + k0 + scol, &Bs[lbase]);
    }
    __syncthreads();  // drains vmcnt -> staged data visible
    for (int kk = 0; kk < 2; ++kk) {
      f16x8 af[4], bf[4];
      const int cofs = (kk * 32 + lg * 8) ^ swzr;
      for (int mt = 0; mt < 4; ++mt)
        af[mt] = *(const f16x8*)&As[(wm * 64 + mt * 16 + lr) * 64 + cofs];
      for (int nt = 0; nt < 4; ++nt)
        bf[nt] = *(const f16x8*)&Bs[(wn * 64 + nt * 16 + lr) * 64 + cofs];
      for (int mt = 0; mt < 4; ++mt)
        for (int nt = 0; nt < 4; ++nt) acc[mt][nt] = MFMA16(af[mt], bf[nt], acc[mt][nt]);
    }
    __syncthreads();  // protect LDS from next stage
  }

  for (int mt = 0; mt < 4; ++mt)
    for (int nt = 0; nt < 4; ++nt) {
      const int gmB = m0 + wm * 64 + mt * 16 + lg * 4;
      const int gn = n0 + wn * 64 + nt * 16 + lr;
      for (int r = 0; r < 4; ++r) {
        const int gm = gmB + r;
        const float v = acc[mt][nt][r];
        if (MODE == 0) {
          const int b = gm >> 11, ns = gm & 2047;
          const int sect = gn >> 10, rem = gn & 1023;
          const int h = rem >> 6, d = rem & 63;
          const size_t bh = (size_t)b * 16 + h;
          if (sect == 0)
            qo[(bh * 2048 + ns) * 64 + d] = (_Float16)(v * QSCALE);  // q*sqrt(d)*log2e
          else if (sect == 1)
            ko[(bh * 2048 + ns) * 64 + d] = (_Float16)v;
          else
            vt[(bh * 64 + d) * 2048 + ns] = (_Float16)v;  // V transposed
        } else {
          fo[(size_t)gm * Nd + gn] = v;
        }
      }
    }
}

// ---------------- flash attention v3 ----------------
// grid (32 qtiles x 32 bh), 4 waves x 16 q-rows, KVBLK=64. XOR-swizzled LDS
// (T2), exp2-domain softmax, T14 issue-early/write-late staging, lane-local
// row sums, skip-rescale on non-growing max, setprio around MFMA.
__global__ __launch_bounds__(256) void attn_kernel(
    const _Float16* __restrict__ Q, const _Float16* __restrict__ K,
    const _Float16* __restrict__ Vt, _Float16* __restrict__ AO) {
  __shared__ __align__(16) _Float16 Kls[64 * 64];      // [key][d], swizzled
  __shared__ __align__(16) _Float16 Vls[64 * 64];      // [d][key], swizzled
  __shared__ __align__(16) _Float16 Pls[4 * 16 * 64];  // per-wave [qrow][key], swizzled
  const int qt = blockIdx.x, bh = blockIdx.y;
  const int b = bh >> 4, h = bh & 15;
  const int tid = threadIdx.x, w = tid >> 6, l = tid & 63;
  const int lr = l & 15, lg = l >> 4;
  const int q0 = qt * 64;
  const int swzr = (lr & 7) << 3;  // read-side XOR (halves)

  f16x8 qf[2];
  {
    const _Float16* qp = Q + ((size_t)bh * 2048 + q0 + w * 16 + lr) * 64 + lg * 8;
    qf[0] = *(const f16x8*)qp;
    qf[1] = *(const f16x8*)(qp + 32);
  }
  float mrun[4], lsum[4];
  f32x4 ao[4];
  for (int r = 0; r < 4; ++r) { mrun[r] = -INFINITY; lsum[r] = 0.f; }
  for (int dt = 0; dt < 4; ++dt) ao[dt] = (f32x4){0.f, 0.f, 0.f, 0.f};

  // staging: thread covers row tid>>2, 16B-blocks (tid&3) and (tid&3)+4
  const int srow = tid >> 2, cb = tid & 3;
  const _Float16* Kbase = K + ((size_t)bh * 2048 + srow) * 64 + cb * 8;
  const _Float16* Vbase = Vt + ((size_t)bh * 64 + srow) * 2048 + cb * 8;
  const int lofs0 = srow * 64 + ((cb ^ (srow & 7)) << 3);
  const int lofs1 = srow * 64 + (((cb + 4) ^ (srow & 7)) << 3);

  f16x8 kr0, kr1, vr0, vr1;
  kr0 = *(const f16x8*)(Kbase);
  kr1 = *(const f16x8*)(Kbase + 32);
  vr0 = *(const f16x8*)(Vbase);
  vr1 = *(const f16x8*)(Vbase + 32);
  *(f16x8*)&Kls[lofs0] = kr0;
  *(f16x8*)&Kls[lofs1] = kr1;
  *(f16x8*)&Vls[lofs0] = vr0;
  *(f16x8*)&Vls[lofs1] = vr1;
  __syncthreads();

  _Float16* pw = &Pls[w * (16 * 64)];
  const int NT = 2048 / 64;
  for (int t = 0; t < NT; ++t) {
    if (t + 1 < NT) {  // issue next tile's loads early (hide HBM under compute)
      const size_t g = (size_t)(t + 1) * 64;
      kr0 = *(const f16x8*)(Kbase + g * 64);
      kr1 = *(const f16x8*)(Kbase + g * 64 + 32);
      vr0 = *(const f16x8*)(Vbase + g);
      vr1 = *(const f16x8*)(Vbase + g + 32);
    }
    // ---- QK^T (exp2-domain: Q pre-scaled by sqrt(d)*log2e) ----
    f32x4 sc[4];
    for (int ct = 0; ct < 4; ++ct) sc[ct] = (f32x4){0.f, 0.f, 0.f, 0.f};
    __builtin_amdgcn_s_setprio(1);
    for (int ct = 0; ct < 4; ++ct)
      for (int kg = 0; kg < 2; ++kg) {
        f16x8 kf = *(const f16x8*)&Kls[(ct * 16 + lr) * 64 + ((kg * 32 + lg * 8) ^ swzr)];
        sc[ct] = MFMA16(qf[kg], kf, sc[ct]);
      }
    __builtin_amdgcn_s_setprio(0);
    // ---- online softmax: row lg*4+r, 64 keys spread over 16 lr x 4 ct ----
    for (int r = 0; r < 4; ++r) {
      float tm = fmaxf(fmaxf(sc[0][r], sc[1][r]), fmaxf(sc[2][r], sc[3][r]));
      tm = fmaxf(tm, __shfl_xor(tm, 1));
      tm = fmaxf(tm, __shfl_xor(tm, 2));
      tm = fmaxf(tm, __shfl_xor(tm, 4));
      tm = fmaxf(tm, __shfl_xor(tm, 8));
      if (tm > mrun[r]) {  // rescale only when the running max grows
        const float corr = exp2f(mrun[r] - tm);
        mrun[r] = tm;
        lsum[r] *= corr;
        for (int dt = 0; dt < 4; ++dt) ao[dt][r] *= corr;
      }
      const float nm = mrun[r];
      const int prow = lg * 4 + r;
      const int pswz = (prow & 7) << 3;
      float ps = 0.f;
      for (int ct = 0; ct < 4; ++ct) {
        const float p = exp2f(sc[ct][r] - nm);
        ps += p;
        pw[prow * 64 + ((ct * 16 + lr) ^ pswz)] = (_Float16)p;
      }
      lsum[r] += ps;  // lane-local partial; reduced once at the end
    }
    // ---- PV ----
    f16x8 pf0 = *(const f16x8*)&pw[lr * 64 + ((lg * 8) ^ swzr)];
    f16x8 pf1 = *(const f16x8*)&pw[lr * 64 + ((32 + lg * 8) ^ swzr)];
    __builtin_amdgcn_s_setprio(1);
    for (int dt = 0; dt < 4; ++dt) {
      f16x8 vf0 = *(const f16x8*)&Vls[(dt * 16 + lr) * 64 + ((lg * 8) ^ swzr)];
      f16x8 vf1 = *(const f16x8*)&Vls[(dt * 16 + lr) * 64 + ((32 + lg * 8) ^ swzr)];
      ao[dt] = MFMA16(pf0, vf0, ao[dt]);
      ao[dt] = MFMA16(pf1, vf1, ao[dt]);
    }
    __builtin_amdgcn_s_setprio(0);
    __syncthreads();  // all waves done reading Kls/Vls
    if (t + 1 < NT) {  // write-late: staged regs -> LDS
      *(f16x8*)&Kls[lofs0] = kr0;
      *(f16x8*)&Kls[lofs1] = kr1;
      *(f16x8*)&Vls[lofs0] = vr0;
      *(f16x8*)&Vls[lofs1] = vr1;
      __syncthreads();
    }
  }
  for (int r = 0; r < 4; ++r) {
    float rs = lsum[r];
    rs += __shfl_xor(rs, 1);
    rs += __shfl_xor(rs, 2);
    rs += __shfl_xor(rs, 4);
    rs += __shfl_xor(rs, 8);
    const float inv = 1.f / rs;
    const int row = q0 + w * 16 + lg * 4 + r;
    for (int dt = 0; dt < 4; ++dt) {
      const int col = h * 64 + dt * 16 + lr;
      AO[((size_t)b * 2048 + row) * 1024 + col] = (_Float16)(ao[dt][r] * inv);
    }
  }
}

extern "C" void kernel_launch(void* const* d_in, const int* in_sizes, int n_in,
                              void* d_out, int out_size, void* d_ws, size_t ws_size,
                              hipStream_t stream) {
  const float* x = (const float*)d_in[0];
  const float* wqkv = (const float*)d_in[2];
  const float* wout = (const float*)d_in[3];
  float* out = (float*)d_out;

  _Float16* xb = (_Float16*)d_ws;                  // 4096*1024
  _Float16* wqkvt = xb + (size_t)4096 * 1024;      // 3072*1024
  _Float16* woutt = wqkvt + (size_t)3072 * 1024;   // 1024*1024
  _Float16* q = woutt + (size_t)1024 * 1024;       // 32*2048*64
  _Float16* k = q + (size_t)4194304;
  _Float16* vt = k + (size_t)4194304;
  _Float16* aobuf = vt + (size_t)4194304;          // 4096*1024

  conv_f32_f16<<<4096, 256, 0, stream>>>(x, xb);
  transpose_f32_f16<<<dim3(96, 32), dim3(32, 8), 0, stream>>>(wqkv, wqkvt, 1024, 3072);
  transpose_f32_f16<<<dim3(32, 32), dim3(32, 8), 0, stream>>>(wout, woutt, 1024, 1024);
  // 1-D grids: 768 = 32 m-tiles x 24 n-tiles; 256 = 32 x 8 (both % 8 == 0)
  gemm128<0><<<768, 256, 0, stream>>>(xb, wqkvt, 1024, q, k, vt, nullptr, 3072);
  attn_kernel<<<dim3(32, 32), 256, 0, stream>>>(q, k, vt, aobuf);
  gemm128<1><<<256, 256, 0, stream>>>(aobuf, woutt, 1024, nullptr, nullptr, nullptr,
                                      out, 1024);
}

// Round 5
// 164.701 us; speedup vs baseline: 1.2520x; 1.2520x over previous
//
#include <hip/hip_runtime.h>
#include <hip/hip_bf16.h>

typedef _Float16 f16x8 __attribute__((ext_vector_type(8)));
typedef _Float16 f16x4 __attribute__((ext_vector_type(4)));
typedef float f32x4 __attribute__((ext_vector_type(4)));
typedef unsigned int u32;

#define MFMA16(a, b, c) __builtin_amdgcn_mfma_f32_16x16x32_f16(a, b, c, 0, 0, 0)

// q pre-scale: sqrt(64) * log2(e)  (exp2-domain softmax)
#define QSCALE 11.54156032f

__device__ __forceinline__ void gld16(const void* g, void* l) {
  using gp_t = const __attribute__((address_space(1))) u32*;
  using lp_t = __attribute__((address_space(3))) u32*;
  __builtin_amdgcn_global_load_lds((gp_t)g, (lp_t)l, 16, 0, 0);
}

// ---------------- fp32 -> fp16 elementwise convert (x) ----------------
__global__ void conv_f32_f16(const float* __restrict__ in, _Float16* __restrict__ out) {
  int i = (blockIdx.x * 256 + threadIdx.x) * 4;
  float4 v = *(const float4*)(in + i);
  f16x4 h = {(_Float16)v.x, (_Float16)v.y, (_Float16)v.z, (_Float16)v.w};
  *(f16x4*)(out + i) = h;
}

// ---------------- fp32 [R][C] -> fp16 [C][R] transpose ----------------
__global__ void transpose_f32_f16(const float* __restrict__ in, _Float16* __restrict__ out,
                                  int R, int C) {
  __shared__ float t[32][33];
  const int tx = threadIdx.x, ty = threadIdx.y;
  const int bx = blockIdx.x * 32, by = blockIdx.y * 32;
  for (int i = 0; i < 32; i += 8)
    t[ty + i][tx] = in[(size_t)(by + ty + i) * C + bx + tx];
  __syncthreads();
  for (int i = 0; i < 32; i += 8)
    out[(size_t)(bx + ty + i) * R + by + tx] = (_Float16)t[tx][ty + i];
}

// ---------------- 128x128 tile GEMM, BK=64: C = A[M][K] * Bt[N][K]^T -------
// (unchanged from R4)
template <int MODE>
__global__ __launch_bounds__(256) void gemm128(
    const _Float16* __restrict__ A, const _Float16* __restrict__ Bt, int Kd,
    _Float16* __restrict__ qo, _Float16* __restrict__ ko, _Float16* __restrict__ vt,
    float* __restrict__ fo, int Nd) {
  __shared__ __align__(16) _Float16 As[128 * 64];
  __shared__ __align__(16) _Float16 Bs[128 * 64];
  const int tid = threadIdx.x;
  const int w = tid >> 6, l = tid & 63;
  const int wm = w >> 1, wn = w & 1;
  const int lr = l & 15, lg = l >> 4;
  const int nwg = gridDim.x;
  int lin = blockIdx.x;
  lin = (lin & 7) * (nwg >> 3) + (lin >> 3);
  const int m0 = (lin & 31) * 128, n0 = (lin >> 5) * 128;

  const int srow = tid >> 3;
  const int scol = ((tid & 7) ^ (srow & 7)) * 8;
  const int swzr = (lr & 7) << 3;

  f32x4 acc[4][4];
  for (int i = 0; i < 4; ++i)
    for (int j = 0; j < 4; ++j) acc[i][j] = (f32x4){0.f, 0.f, 0.f, 0.f};

  const int NT = Kd >> 6;
  for (int kt = 0; kt < NT; ++kt) {
    const int k0 = kt * 64;
    for (int c = 0; c < 4; ++c) {
      const int row = c * 32 + srow;
      const int lbase = (c * 32 + w * 8) * 64;
      gld16(A + (size_t)(m0 + row) * Kd + k0 + scol, &As[lbase]);
      gld16(Bt + (size_t)(n0 + row) * Kd + k0 + scol, &Bs[lbase]);
    }
    __syncthreads();
    for (int kk = 0; kk < 2; ++kk) {
      f16x8 af[4], bf[4];
      const int cofs = (kk * 32 + lg * 8) ^ swzr;
      for (int mt = 0; mt < 4; ++mt)
        af[mt] = *(const f16x8*)&As[(wm * 64 + mt * 16 + lr) * 64 + cofs];
      for (int nt = 0; nt < 4; ++nt)
        bf[nt] = *(const f16x8*)&Bs[(wn * 64 + nt * 16 + lr) * 64 + cofs];
      for (int mt = 0; mt < 4; ++mt)
        for (int nt = 0; nt < 4; ++nt) acc[mt][nt] = MFMA16(af[mt], bf[nt], acc[mt][nt]);
    }
    __syncthreads();
  }

  for (int mt = 0; mt < 4; ++mt)
    for (int nt = 0; nt < 4; ++nt) {
      const int gmB = m0 + wm * 64 + mt * 16 + lg * 4;
      const int gn = n0 + wn * 64 + nt * 16 + lr;
      for (int r = 0; r < 4; ++r) {
        const int gm = gmB + r;
        const float v = acc[mt][nt][r];
        if (MODE == 0) {
          const int b = gm >> 11, ns = gm & 2047;
          const int sect = gn >> 10, rem = gn & 1023;
          const int h = rem >> 6, d = rem & 63;
          const size_t bh = (size_t)b * 16 + h;
          if (sect == 0)
            qo[(bh * 2048 + ns) * 64 + d] = (_Float16)(v * QSCALE);
          else if (sect == 1)
            ko[(bh * 2048 + ns) * 64 + d] = (_Float16)v;
          else
            vt[(bh * 64 + d) * 2048 + ns] = (_Float16)v;
        } else {
          fo[(size_t)gm * Nd + gn] = v;
        }
      }
    }
}

// ---------------- flash attention v4 ----------------
// Swapped QK^T: sc = mfma(K, Q) -> S^T[key][q]; each lane owns ONE q-row
// (q = w*16 + lr) with 16 keys (16ct+4lg+r). Softmax: 15 local fmax + 2
// shuffles; single (m,l) state/lane; rescale under wave-uniform __any;
// P written as 4x ds_write_b64 (f16x4 = 4 consecutive keys).
__global__ __launch_bounds__(256) void attn_kernel(
    const _Float16* __restrict__ Q, const _Float16* __restrict__ K,
    const _Float16* __restrict__ Vt, _Float16* __restrict__ AO) {
  __shared__ __align__(16) _Float16 Kls[64 * 64];      // [key][d], swizzled
  __shared__ __align__(16) _Float16 Vls[64 * 64];      // [d][key], swizzled
  __shared__ __align__(16) _Float16 Pls[4 * 16 * 64];  // per-wave [q][key], swizzled
  const int qt = blockIdx.x, bh = blockIdx.y;
  const int b = bh >> 4, h = bh & 15;
  const int tid = threadIdx.x, w = tid >> 6, l = tid & 63;
  const int lr = l & 15, lg = l >> 4;
  const int q0 = qt * 64;
  const int pswz = (lr & 7) << 3;  // row=lr XOR swizzle (halves)

  f16x8 qf[2];
  {
    const _Float16* qp = Q + ((size_t)bh * 2048 + q0 + w * 16 + lr) * 64 + lg * 8;
    qf[0] = *(const f16x8*)qp;
    qf[1] = *(const f16x8*)(qp + 32);
  }
  float mrun = -INFINITY, lsum = 0.f;  // state for q = w*16 + lr
  f32x4 ao[4];
  for (int dt = 0; dt < 4; ++dt) ao[dt] = (f32x4){0.f, 0.f, 0.f, 0.f};

  // staging: thread covers row tid>>2, 16B-blocks (tid&3) and (tid&3)+4
  const int srow = tid >> 2, cb = tid & 3;
  const _Float16* Kbase = K + ((size_t)bh * 2048 + srow) * 64 + cb * 8;
  const _Float16* Vbase = Vt + ((size_t)bh * 64 + srow) * 2048 + cb * 8;
  const int lofs0 = srow * 64 + ((cb ^ (srow & 7)) << 3);
  const int lofs1 = srow * 64 + (((cb + 4) ^ (srow & 7)) << 3);

  f16x8 kr0, kr1, vr0, vr1;
  kr0 = *(const f16x8*)(Kbase);
  kr1 = *(const f16x8*)(Kbase + 32);
  vr0 = *(const f16x8*)(Vbase);
  vr1 = *(const f16x8*)(Vbase + 32);
  *(f16x8*)&Kls[lofs0] = kr0;
  *(f16x8*)&Kls[lofs1] = kr1;
  *(f16x8*)&Vls[lofs0] = vr0;
  *(f16x8*)&Vls[lofs1] = vr1;
  __syncthreads();

  _Float16* pw = &Pls[w * (16 * 64)];
  const int NT = 2048 / 64;
  for (int t = 0; t < NT; ++t) {
    if (t + 1 < NT) {  // issue next tile's loads early
      const size_t g = (size_t)(t + 1) * 64;
      kr0 = *(const f16x8*)(Kbase + g * 64);
      kr1 = *(const f16x8*)(Kbase + g * 64 + 32);
      vr0 = *(const f16x8*)(Vbase + g);
      vr1 = *(const f16x8*)(Vbase + g + 32);
    }
    // ---- S^T = K (Q pre-scaled) : sc[ct][r] = S[key=16ct+4lg+r][q=w*16+lr]
    f32x4 sc[4];
    for (int ct = 0; ct < 4; ++ct) sc[ct] = (f32x4){0.f, 0.f, 0.f, 0.f};
    __builtin_amdgcn_s_setprio(1);
    for (int ct = 0; ct < 4; ++ct)
      for (int kg = 0; kg < 2; ++kg) {
        f16x8 kf = *(const f16x8*)&Kls[(ct * 16 + lr) * 64 + ((kg * 32 + lg * 8) ^ pswz)];
        sc[ct] = MFMA16(kf, qf[kg], sc[ct]);
      }
    __builtin_amdgcn_s_setprio(0);
    // ---- softmax over this lane's 16 keys + 2-lane-hop reduce ----
    float tm = fmaxf(fmaxf(fmaxf(sc[0][0], sc[0][1]), fmaxf(sc[0][2], sc[0][3])),
                     fmaxf(fmaxf(sc[1][0], sc[1][1]), fmaxf(sc[1][2], sc[1][3])));
    tm = fmaxf(tm, fmaxf(fmaxf(fmaxf(sc[2][0], sc[2][1]), fmaxf(sc[2][2], sc[2][3])),
                         fmaxf(fmaxf(sc[3][0], sc[3][1]), fmaxf(sc[3][2], sc[3][3]))));
    tm = fmaxf(tm, __shfl_xor(tm, 16));
    tm = fmaxf(tm, __shfl_xor(tm, 32));
    if (__any(tm > mrun)) {  // rescale only when some row's max grows
      const float nm = fmaxf(mrun, tm);
      const float corr = exp2f(mrun - nm);
      mrun = nm;
      lsum *= corr;
      float cr[4];
      for (int r = 0; r < 4; ++r) cr[r] = __shfl(corr, lg * 4 + r);
      for (int dt = 0; dt < 4; ++dt)
        for (int r = 0; r < 4; ++r) ao[dt][r] *= cr[r];
    }
    float ps = 0.f;
    for (int ct = 0; ct < 4; ++ct) {
      f16x4 ph;
      for (int r = 0; r < 4; ++r) {
        const float p = exp2f(sc[ct][r] - mrun);
        ps += p;
        ph[r] = (_Float16)p;
      }
      *(f16x4*)&pw[lr * 64 + ((ct * 16 + lg * 4) ^ pswz)] = ph;
    }
    lsum += ps;
    // ---- PV ----
    f16x8 pf0 = *(const f16x8*)&pw[lr * 64 + ((lg * 8) ^ pswz)];
    f16x8 pf1 = *(const f16x8*)&pw[lr * 64 + ((32 + lg * 8) ^ pswz)];
    __builtin_amdgcn_s_setprio(1);
    for (int dt = 0; dt < 4; ++dt) {
      f16x8 vf0 = *(const f16x8*)&Vls[(dt * 16 + lr) * 64 + ((lg * 8) ^ pswz)];
      f16x8 vf1 = *(const f16x8*)&Vls[(dt * 16 + lr) * 64 + ((32 + lg * 8) ^ pswz)];
      ao[dt] = MFMA16(pf0, vf0, ao[dt]);
      ao[dt] = MFMA16(pf1, vf1, ao[dt]);
    }
    __builtin_amdgcn_s_setprio(0);
    __syncthreads();  // all waves done reading Kls/Vls
    if (t + 1 < NT) {  // write-late: staged regs -> LDS
      *(f16x8*)&Kls[lofs0] = kr0;
      *(f16x8*)&Kls[lofs1] = kr1;
      *(f16x8*)&Vls[lofs0] = vr0;
      *(f16x8*)&Vls[lofs1] = vr1;
      __syncthreads();
    }
  }
  // final: total sum for q=w*16+lr, then shuffle inverse to ao rows (lg*4+r)
  lsum += __shfl_xor(lsum, 16);
  lsum += __shfl_xor(lsum, 32);
  const float inv = 1.f / lsum;
  float invr[4];
  for (int r = 0; r < 4; ++r) invr[r] = __shfl(inv, lg * 4 + r);
  for (int r = 0; r < 4; ++r) {
    const int row = q0 + w * 16 + lg * 4 + r;
    for (int dt = 0; dt < 4; ++dt) {
      const int col = h * 64 + dt * 16 + lr;
      AO[((size_t)b * 2048 + row) * 1024 + col] = (_Float16)(ao[dt][r] * invr[r]);
    }
  }
}

extern "C" void kernel_launch(void* const* d_in, const int* in_sizes, int n_in,
                              void* d_out, int out_size, void* d_ws, size_t ws_size,
                              hipStream_t stream) {
  const float* x = (const float*)d_in[0];
  const float* wqkv = (const float*)d_in[2];
  const float* wout = (const float*)d_in[3];
  float* out = (float*)d_out;

  _Float16* xb = (_Float16*)d_ws;                  // 4096*1024
  _Float16* wqkvt = xb + (size_t)4096 * 1024;      // 3072*1024
  _Float16* woutt = wqkvt + (size_t)3072 * 1024;   // 1024*1024
  _Float16* q = woutt + (size_t)1024 * 1024;       // 32*2048*64
  _Float16* k = q + (size_t)4194304;
  _Float16* vt = k + (size_t)4194304;
  _Float16* aobuf = vt + (size_t)4194304;          // 4096*1024

  conv_f32_f16<<<4096, 256, 0, stream>>>(x, xb);
  transpose_f32_f16<<<dim3(96, 32), dim3(32, 8), 0, stream>>>(wqkv, wqkvt, 1024, 3072);
  transpose_f32_f16<<<dim3(32, 32), dim3(32, 8), 0, stream>>>(wout, woutt, 1024, 1024);
  gemm128<0><<<768, 256, 0, stream>>>(xb, wqkvt, 1024, q, k, vt, nullptr, 3072);
  attn_kernel<<<dim3(32, 32), 256, 0, stream>>>(q, k, vt, aobuf);
  gemm128<1><<<256, 256, 0, stream>>>(aobuf, woutt, 1024, nullptr, nullptr, nullptr,
                                      out, 1024);
}